// Round 17
// baseline (331.444 us; speedup 1.0000x reference)
//
#include <hip/hip_runtime.h>
#include <math.h>

#define N_NODES 100000
#define N_EDGES 1600000
#define HD 64
#define TILE 128
#define NBUCK 128          // dst>>10 -> 98 used buckets
#define BNODES 1024
#define EPB 4096           // edges per block in hist/reorder

typedef unsigned short ushort_t;
typedef unsigned char uchar_t;
typedef __attribute__((ext_vector_type(8))) unsigned short ushort8_t;
typedef __attribute__((ext_vector_type(8))) short short8_t;
typedef __attribute__((ext_vector_type(4))) float float4_t;
typedef __attribute__((ext_vector_type(2))) float float2_t;

__device__ __forceinline__ float bf2f(ushort_t h){
  union{unsigned u; float f;} v; v.u = ((unsigned)h)<<16; return v.f;
}
__device__ __forceinline__ ushort_t f2bf(float f){
  union{float f; unsigned u;} v; v.f=f;
  unsigned b = v.u + 0x7FFF + ((v.u>>16)&1);
  return (ushort_t)(b>>16);
}
__device__ __forceinline__ void acc8(float* acc, unsigned ux, unsigned uy, float m){
  float2_t f;
  f=__builtin_amdgcn_cvt_pk_f32_fp8((int)ux,false); acc[0]=fmaf(m,f.x,acc[0]); acc[1]=fmaf(m,f.y,acc[1]);
  f=__builtin_amdgcn_cvt_pk_f32_fp8((int)ux,true ); acc[2]=fmaf(m,f.x,acc[2]); acc[3]=fmaf(m,f.y,acc[3]);
  f=__builtin_amdgcn_cvt_pk_f32_fp8((int)uy,false); acc[4]=fmaf(m,f.x,acc[4]); acc[5]=fmaf(m,f.y,acc[5]);
  f=__builtin_amdgcn_cvt_pk_f32_fp8((int)uy,true ); acc[6]=fmaf(m,f.x,acc[6]); acc[7]=fmaf(m,f.y,acc[7]);
}
__device__ __forceinline__ void acc16(float* acc, uint4 u, float m){
  acc8(acc,   u.x, u.y, m);
  acc8(acc+8, u.z, u.w, m);
}

// fused convert: x f32 -> bf16 copy + fp8(e4m3) copy; block 0 also zeroes bcnt
__global__ void k_convert_x(const float* __restrict__ in, ushort_t* __restrict__ obf,
                            uchar_t* __restrict__ o8, int* __restrict__ bcnt, int n){
  int i = blockIdx.x*blockDim.x + threadIdx.x;
  if(blockIdx.x==0 && threadIdx.x<NBUCK) bcnt[threadIdx.x]=0;
  int idx = i*4;
  if(idx+3<n){
    float4 v = *(const float4*)&in[idx];
    ushort2 a; a.x=f2bf(v.x); a.y=f2bf(v.y);
    ushort2 b; b.x=f2bf(v.z); b.y=f2bf(v.w);
    *(ushort2*)&obf[idx] = a;
    *(ushort2*)&obf[idx+2] = b;
    int p = __builtin_amdgcn_cvt_pk_fp8_f32(v.x, v.y, 0, false);
    p     = __builtin_amdgcn_cvt_pk_fp8_f32(v.z, v.w, p, true);
    *(unsigned int*)&o8[idx] = (unsigned int)p;
  } else {
    for(int k=idx;k<n;k++){
      obf[k]=f2bf(in[k]);
      int p = __builtin_amdgcn_cvt_pk_fp8_f32(in[k], 0.f, 0, false);
      o8[k] = (uchar_t)(p & 0xFF);
    }
  }
}

// ---- CSR build: coarse radix partition by dst>>10, then per-bucket finalize ----

__global__ __launch_bounds__(512) void k_hist(const int* __restrict__ dst, int* __restrict__ bcnt, int n){
  __shared__ int lh[NBUCK];
  int t=threadIdx.x;
  if(t<NBUCK) lh[t]=0;
  __syncthreads();
  int base = blockIdx.x*EPB;
  #pragma unroll
  for(int j=0;j<8;j++){
    int e = base + t + j*512;
    if(e<n) atomicAdd(&lh[dst[e]>>10], 1);
  }
  __syncthreads();
  if(t<NBUCK && lh[t]) atomicAdd(&bcnt[t], lh[t]);
}

__global__ void k_scan128(const int* __restrict__ bcnt, int* __restrict__ gcur, int* __restrict__ gbase){
  __shared__ int s[NBUCK];
  int t=threadIdx.x;
  int v=bcnt[t]; s[t]=v;
  __syncthreads();
  for(int off=1; off<NBUCK; off<<=1){
    int a=(t>=off)? s[t-off]:0;
    __syncthreads();
    s[t]+=a;
    __syncthreads();
  }
  int excl = s[t]-v;
  gcur[t]=excl;
  gbase[t]=excl;
  if(t==NBUCK-1) gbase[NBUCK]=s[t];
}

// packed pair: src (17b) | dstlocal<<17 (10b)
__global__ __launch_bounds__(512) void k_reorder(
    const int* __restrict__ src, const int* __restrict__ dst,
    int* __restrict__ gcur, int* __restrict__ pairs, int n){
  __shared__ int lh[NBUCK];
  __shared__ int lbase[NBUCK];
  int t=threadIdx.x;
  if(t<NBUCK) lh[t]=0;
  __syncthreads();
  int base = blockIdx.x*EPB;
  int bb[8], rr[8], pv[8];
  #pragma unroll
  for(int j=0;j<8;j++){
    int e = base + t + j*512;
    if(e<n){
      int d=dst[e];
      int b=d>>10;
      rr[j]=atomicAdd(&lh[b],1);
      bb[j]=b;
      pv[j]=src[e] | ((d & 1023)<<17);
    } else bb[j]=-1;
  }
  __syncthreads();
  if(t<NBUCK && lh[t]) lbase[t]=atomicAdd(&gcur[t], lh[t]);
  __syncthreads();
  #pragma unroll
  for(int j=0;j<8;j++){
    if(bb[j]>=0){
      int pos = lbase[bb[j]] + rr[j];
      pairs[pos] = pv[j];
    }
  }
}

// One block per bucket: LDS hist over 1024 local nodes -> scan -> rowptr/invdeg
// -> LDS-cursor scatter into the bucket's private csr window (one XCD's L2).
__global__ __launch_bounds__(512) void k_bucket_csr(
    const int* __restrict__ pairs, const int* __restrict__ gbase,
    int* __restrict__ rowptr, float* __restrict__ invdeg,
    int* __restrict__ csr, int nnodes, int nedges){
  __shared__ int cnt[BNODES];
  __shared__ int part[512];
  int t=threadIdx.x, b=blockIdx.x;
  int nb0 = b*BNODES;
  int e0 = gbase[b], e1 = gbase[b+1];
  cnt[t]=0; cnt[t+512]=0;
  __syncthreads();
  for(int e=e0+t; e<e1; e+=512) atomicAdd(&cnt[pairs[e]>>17], 1);
  __syncthreads();
  int c0 = cnt[2*t], c1 = cnt[2*t+1];
  part[t] = c0+c1;
  __syncthreads();
  for(int off=1; off<512; off<<=1){
    int a=(t>=off)? part[t-off]:0;
    __syncthreads();
    part[t]+=a;
    __syncthreads();
  }
  int base = part[t]-(c0+c1);
  int ex0 = base, ex1 = base+c0;
  int n_0 = nb0+2*t, n_1 = nb0+2*t+1;
  if(n_0<nnodes){ rowptr[n_0]=e0+ex0; invdeg[n_0]=1.0f/fmaxf((float)c0,1.0f); }
  if(n_1<nnodes){ rowptr[n_1]=e0+ex1; invdeg[n_1]=1.0f/fmaxf((float)c1,1.0f); }
  if(b==0 && t==0) rowptr[nnodes]=nedges;
  cnt[2*t]=ex0; cnt[2*t+1]=ex1;      // become cursors
  __syncthreads();
  for(int e=e0+t; e<e1; e+=512){
    int p = pairs[e];
    int pos = atomicAdd(&cnt[p>>17], 1);
    csr[e0+pos] = p & 0x1FFFF;
  }
}

// fp8 gather: TWO nodes per wave, 16B per lane. slot = lane>>2 (16 edge slots),
// c = lane&3 (16B chunk = 16 fp8 features). ONE VMEM instruction gathers 16
// edges (16 distinct 64B lines); both nodes' first batches issued back-to-back
// -> 32 lines in flight per wave. agg[node] = mean of neighbor rows -> bf16.
__global__ __launch_bounds__(512, 8) void k_gather(
    const uchar_t* __restrict__ hin8, ushort_t* __restrict__ agg,
    const int* __restrict__ rowptr, const int* __restrict__ csr,
    const float* __restrict__ invdeg, int nnodes)
{
  int t=threadIdx.x;
  int lane=t&63, wid=t>>6;
  int nA=(blockIdx.x*8+wid)*2;
  if(nA>=nnodes) return;
  int nB=nA+1;
  bool hasB = (nB<nnodes);
  int slot=lane>>2, c=lane&3;
  int rA0=rowptr[nA], rA1=rowptr[nA+1];
  int rB0=rA1, rB1=hasB? rowptr[nB+1] : rA1;
  float idgA=invdeg[nA];
  float idgB=hasB? invdeg[nB] : 0.f;
  float aA[16], aB[16];
  #pragma unroll
  for(int j=0;j<16;j++){ aA[j]=0.f; aB[j]=0.f; }
  int ca = (rA1>rA0)? rA1-1 : 0;
  int cb = (rB1>rB0)? rB1-1 : 0;

  {  // prologue: batch0 of A and B in flight together
    int iA=rA0+slot, iB=rB0+slot;
    int sA=csr[min(iA,ca)], sB=csr[min(iB,cb)];
    uint4 uA=*(const uint4*)&hin8[(size_t)sA*HD + c*16];
    uint4 uB=*(const uint4*)&hin8[(size_t)sB*HD + c*16];
    acc16(aA,uA,(iA<rA1)?1.f:0.f);
    acc16(aB,uB,(iB<rB1)?1.f:0.f);
  }
  for(int e=rA0+16; e<rA1; e+=16){
    int i=e+slot;
    int s=csr[min(i,ca)];
    uint4 u=*(const uint4*)&hin8[(size_t)s*HD + c*16];
    acc16(aA,u,(i<rA1)?1.f:0.f);
  }
  for(int e=rB0+16; e<rB1; e+=16){
    int i=e+slot;
    int s=csr[min(i,cb)];
    uint4 u=*(const uint4*)&hin8[(size_t)s*HD + c*16];
    acc16(aB,u,(i<rB1)?1.f:0.f);
  }
  // reduce across the 16 edge slots (lane bits 2..5)
  #pragma unroll
  for(int off=4; off<64; off<<=1){
    #pragma unroll
    for(int j=0;j<16;j++){
      aA[j] += __shfl_xor(aA[j], off, 64);
      aB[j] += __shfl_xor(aB[j], off, 64);
    }
  }
  if(slot==0){
    ushort8_t o;
    #pragma unroll
    for(int j=0;j<8;j++) o[j] = f2bf(aA[j]*idgA);
    *(ushort8_t*)&agg[(size_t)nA*HD + c*16] = o;
    #pragma unroll
    for(int j=0;j<8;j++) o[j] = f2bf(aA[8+j]*idgA);
    *(ushort8_t*)&agg[(size_t)nA*HD + c*16 + 8] = o;
    if(hasB){
      #pragma unroll
      for(int j=0;j<8;j++) o[j] = f2bf(aB[j]*idgB);
      *(ushort8_t*)&agg[(size_t)nB*HD + c*16] = o;
      #pragma unroll
      for(int j=0;j<8;j++) o[j] = f2bf(aB[8+j]*idgB);
      *(ushort8_t*)&agg[(size_t)nB*HD + c*16 + 8] = o;
    }
  }
}

// MFMA dense: C[N,64] = relu([agg|h] @ [Wl;Wr] + b), fused JK dot (+sigmoid).
// Epilogue also emits the fp8 copy of h for the next layer's gather.
__global__ __launch_bounds__(256) void k_dense(
    const ushort_t* __restrict__ hin, const ushort_t* __restrict__ agg,
    ushort_t* __restrict__ hout, uchar_t* __restrict__ h8out,
    const float* __restrict__ Wl, const float* __restrict__ bvec, const float* __restrict__ Wr,
    const float* __restrict__ wseg, const float* __restrict__ blin,
    float* __restrict__ partial, float* __restrict__ finout,
    int first, int nnodes)
{
  __shared__ ushort_t sWt[64][136];   // W^T bf16: [col][k]; 272B stride -> 2-way (free)
  __shared__ ushort_t sOut[TILE][72]; // relu'd outputs bf16
  __shared__ float sB[64], sS[64];
  int t = threadIdx.x;
  int n0 = blockIdx.x*TILE;

  {
    int col = t & 63;
    int k0  = (t >> 6) * 32;
    #pragma unroll
    for (int j = 0; j < 32; ++j) {
      int k = k0 + j;
      float wv = (k < 64) ? Wl[k*64 + col] : Wr[(k-64)*64 + col];
      sWt[col][k] = f2bf(wv);
    }
  }
  if(t<64){ sB[t]=bvec[t]; sS[t]=wseg[t]; }
  __syncthreads();

  int lane = t & 63, wv_ = t >> 6;
  int r16 = lane & 15, g4 = lane >> 4;
  int nbase = n0 + wv_*32;

  float4_t acc[2][4];
  #pragma unroll
  for(int mt=0;mt<2;mt++)
    #pragma unroll
    for(int ct=0;ct<4;ct++)
      #pragma unroll
      for(int r=0;r<4;r++) acc[mt][ct][r]=0.f;

  #pragma unroll
  for (int ks = 0; ks < 4; ++ks) {
    const ushort_t* abuf = (ks < 2) ? agg : hin;   // k<64: agg, k>=64: h
    int koff = (ks & 1)*32 + g4*8;
    short8_t aF[2];
    #pragma unroll
    for (int mt = 0; mt < 2; ++mt) {
      int node = nbase + mt*16 + r16;
      if (node >= nnodes) node = nnodes-1;         // clamp; stores guarded
      aF[mt] = *(const short8_t*)&abuf[(size_t)node*HD + koff];
    }
    #pragma unroll
    for (int ct = 0; ct < 4; ++ct) {
      short8_t bF = *(const short8_t*)&sWt[ct*16 + r16][ks*32 + g4*8];
      acc[0][ct] = __builtin_amdgcn_mfma_f32_16x16x32_bf16(aF[0], bF, acc[0][ct], 0,0,0);
      acc[1][ct] = __builtin_amdgcn_mfma_f32_16x16x32_bf16(aF[1], bF, acc[1][ct], 0,0,0);
    }
  }

  #pragma unroll
  for (int mt = 0; mt < 2; ++mt)
    #pragma unroll
    for (int ct = 0; ct < 4; ++ct) {
      int col = ct*16 + r16;
      #pragma unroll
      for (int r = 0; r < 4; ++r) {
        int row = g4*4 + r;
        float v = fmaxf(acc[mt][ct][r] + sB[col], 0.f);
        sOut[wv_*32 + mt*16 + row][col] = f2bf(v);
      }
    }
  __syncthreads();

  // pass 2: vectorized stores (bf16 + fp8) + JK dot + partial/sigmoid
  {
    int nl = t >> 1, half = t & 1;
    int node = n0 + nl;
    float p = 0.f;
    #pragma unroll
    for (int i = 0; i < 4; ++i) {
      int c0 = half*32 + i*8;
      ushort8_t v = *(const ushort8_t*)&sOut[nl][c0];
      float fv[8];
      #pragma unroll
      for (int j = 0; j < 8; ++j){ fv[j]=bf2f(v[j]); p = fmaf(fv[j], sS[c0+j], p); }
      if (!finout && node < nnodes){
        *(ushort8_t*)&hout[(size_t)node*HD + c0] = v;
        int q0 = __builtin_amdgcn_cvt_pk_fp8_f32(fv[0], fv[1], 0, false);
        q0     = __builtin_amdgcn_cvt_pk_fp8_f32(fv[2], fv[3], q0, true);
        int q1 = __builtin_amdgcn_cvt_pk_fp8_f32(fv[4], fv[5], 0, false);
        q1     = __builtin_amdgcn_cvt_pk_fp8_f32(fv[6], fv[7], q1, true);
        uint2 st; st.x=(unsigned)q0; st.y=(unsigned)q1;
        *(uint2*)&h8out[(size_t)node*HD + c0] = st;
      }
    }
    p += __shfl_xor(p, 1, 64);
    if (half == 0 && node < nnodes) {
      float q = first ? (blin[0] + p) : (partial[node] + p);
      if (finout) finout[node] = 1.0f/(1.0f+expf(-q));
      else partial[node] = q;
    }
  }
}

extern "C" void kernel_launch(void* const* d_in, const int* in_sizes, int n_in,
                              void* d_out, int out_size, void* d_ws, size_t ws_size,
                              hipStream_t stream){
  const float* x    =(const float*)d_in[0];
  const int*   ei   =(const int*)  d_in[1];
  const float* W1l  =(const float*)d_in[2];
  const float* b1   =(const float*)d_in[3];
  const float* W1r  =(const float*)d_in[4];
  const float* W2l  =(const float*)d_in[5];
  const float* b2   =(const float*)d_in[6];
  const float* W2r  =(const float*)d_in[7];
  const float* W3l  =(const float*)d_in[8];
  const float* b3   =(const float*)d_in[9];
  const float* W3r  =(const float*)d_in[10];
  const float* Wlin =(const float*)d_in[11];
  const float* blin =(const float*)d_in[12];
  float* out=(float*)d_out;

  const int N=N_NODES, E=N_EDGES;
  char* ws=(char*)d_ws;
  size_t off=0;
  auto take=[&](size_t bytes)->char*{ char* p=ws+off; off=(off+bytes+255)&~(size_t)255; return p; };
  int*      bcnt     =(int*)     take((size_t)NBUCK*4);
  int*      gcur     =(int*)     take((size_t)NBUCK*4);
  int*      gbase    =(int*)     take((size_t)(NBUCK+1)*4);
  int*      rowptr   =(int*)     take((size_t)(N+1)*4);
  int*      csr      =(int*)     take((size_t)E*4);
  int*      pairs    =(int*)     take((size_t)E*4);
  float*    invdeg   =(float*)   take((size_t)N*4);
  ushort_t* xbf      =(ushort_t*)take((size_t)N*HD*2);
  ushort_t* hbfA     =(ushort_t*)take((size_t)N*HD*2);
  ushort_t* hbfB     =(ushort_t*)take((size_t)N*HD*2);
  ushort_t* aggbf    =(ushort_t*)take((size_t)N*HD*2);
  uchar_t*  x8       =(uchar_t*) take((size_t)N*HD);
  uchar_t*  h8A      =(uchar_t*) take((size_t)N*HD);
  uchar_t*  h8B      =(uchar_t*) take((size_t)N*HD);
  float*    pacc     =(float*)   take((size_t)N*4);

  const int RB=(E+EPB-1)/EPB;           // 391 (hist/reorder)
  const int CB=(N*HD/4+255)/256;        // convert blocks
  const int BB=(N+BNODES-1)/BNODES;     // 98 buckets

  k_convert_x  <<<CB, 256, 0, stream>>>(x, xbf, x8, bcnt, N*HD);
  k_hist       <<<RB, 512, 0, stream>>>(ei+E, bcnt, E);
  k_scan128    <<<1, NBUCK, 0, stream>>>(bcnt, gcur, gbase);
  k_reorder    <<<RB, 512, 0, stream>>>(ei, ei+E, gcur, pairs, E);
  k_bucket_csr <<<BB, 512, 0, stream>>>(pairs, gbase, rowptr, invdeg, csr, N, E);

  dim3 gg((N+15)/16);                   // 6250 blocks, 2 nodes/wave
  dim3 gd((N+TILE-1)/TILE);

  k_gather<<<gg, 512, 0, stream>>>(x8,  aggbf, rowptr, csr, invdeg, N);
  k_dense <<<gd, 256, 0, stream>>>(xbf,  aggbf, hbfA, h8A, W1l,b1,W1r, Wlin+0,   blin, pacc, (float*)nullptr, 1, N);
  k_gather<<<gg, 512, 0, stream>>>(h8A, aggbf, rowptr, csr, invdeg, N);
  k_dense <<<gd, 256, 0, stream>>>(hbfA, aggbf, hbfB, h8B, W2l,b2,W2r, Wlin+64,  blin, pacc, (float*)nullptr, 0, N);
  k_gather<<<gg, 512, 0, stream>>>(h8B, aggbf, rowptr, csr, invdeg, N);
  k_dense <<<gd, 256, 0, stream>>>(hbfB, aggbf, hbfA, h8A, W3l,b3,W3r, Wlin+128, blin, pacc, out, 0, N);
}

// Round 18
// 196.716 us; speedup vs baseline: 1.6849x; 1.6849x over previous
//
#include <hip/hip_runtime.h>
#include <math.h>

#define N_NODES 100000
#define N_EDGES 1600000
#define HD 64
#define TILE 128
#define NBUCK 128          // dst>>10 -> 98 used buckets
#define BNODES 1024
#define EPB 4096           // edges per block in reorder
#define EPB2 8192          // edges per block in fused hist
#define HB 196             // hist blocks = ceil(E/EPB2)

typedef unsigned short ushort_t;
typedef unsigned char uchar_t;
typedef __attribute__((ext_vector_type(8))) unsigned short ushort8_t;
typedef __attribute__((ext_vector_type(8))) short short8_t;
typedef __attribute__((ext_vector_type(4))) float float4_t;
typedef __attribute__((ext_vector_type(2))) float float2_t;

__device__ __forceinline__ float bf2f(ushort_t h){
  union{unsigned u; float f;} v; v.u = ((unsigned)h)<<16; return v.f;
}
__device__ __forceinline__ ushort_t f2bf(float f){
  union{float f; unsigned u;} v; v.f=f;
  unsigned b = v.u + 0x7FFF + ((v.u>>16)&1);
  return (ushort_t)(b>>16);
}
__device__ __forceinline__ void acc8(float* acc, unsigned ux, unsigned uy, float m){
  float2_t f;
  f=__builtin_amdgcn_cvt_pk_f32_fp8((int)ux,false); acc[0]=fmaf(m,f.x,acc[0]); acc[1]=fmaf(m,f.y,acc[1]);
  f=__builtin_amdgcn_cvt_pk_f32_fp8((int)ux,true ); acc[2]=fmaf(m,f.x,acc[2]); acc[3]=fmaf(m,f.y,acc[3]);
  f=__builtin_amdgcn_cvt_pk_f32_fp8((int)uy,false); acc[4]=fmaf(m,f.x,acc[4]); acc[5]=fmaf(m,f.y,acc[5]);
  f=__builtin_amdgcn_cvt_pk_f32_fp8((int)uy,true ); acc[6]=fmaf(m,f.x,acc[6]); acc[7]=fmaf(m,f.y,acc[7]);
}

// fused: x f32 -> bf16 + fp8 copies; blocks < HB also build a PRIVATE dst
// histogram (bcnt2d[b][bucket]) -- no global atomics, no zeroing needed.
__global__ __launch_bounds__(512) void k_convert_hist(
    const float* __restrict__ in, ushort_t* __restrict__ obf, uchar_t* __restrict__ o8,
    const int* __restrict__ dst, int* __restrict__ bcnt2d, int nfeat, int nedge){
  __shared__ int lh[NBUCK];
  int t=threadIdx.x, b=blockIdx.x;
  bool doHist = (b < HB);
  if(doHist){
    if(t<NBUCK) lh[t]=0;
    __syncthreads();
    int base=b*EPB2;
    #pragma unroll
    for(int j=0;j<16;j++){
      int e=base+t+j*512;
      if(e<nedge) atomicAdd(&lh[dst[e]>>10],1);
    }
  }
  int idx = (b*512+t)*4;
  if(idx+3<nfeat){
    float4 v = *(const float4*)&in[idx];
    ushort2 a; a.x=f2bf(v.x); a.y=f2bf(v.y);
    ushort2 c2; c2.x=f2bf(v.z); c2.y=f2bf(v.w);
    *(ushort2*)&obf[idx] = a;
    *(ushort2*)&obf[idx+2] = c2;
    int p = __builtin_amdgcn_cvt_pk_fp8_f32(v.x, v.y, 0, false);
    p     = __builtin_amdgcn_cvt_pk_fp8_f32(v.z, v.w, p, true);
    *(unsigned int*)&o8[idx] = (unsigned int)p;
  } else {
    for(int k=idx;k<nfeat;k++){
      obf[k]=f2bf(in[k]);
      int p = __builtin_amdgcn_cvt_pk_fp8_f32(in[k], 0.f, 0, false);
      o8[k] = (uchar_t)(p & 0xFF);
    }
  }
  if(doHist){
    __syncthreads();
    if(t<NBUCK) bcnt2d[b*NBUCK+t]=lh[t];
  }
}

// sum private hists -> bucket totals -> exclusive scan
__global__ void k_scan128(const int* __restrict__ bcnt2d, int* __restrict__ gcur, int* __restrict__ gbase){
  __shared__ int s[NBUCK];
  int t=threadIdx.x;
  int v=0;
  int b=0;
  for(; b+4<=HB; b+=4)
    v += bcnt2d[b*NBUCK+t] + bcnt2d[(b+1)*NBUCK+t] + bcnt2d[(b+2)*NBUCK+t] + bcnt2d[(b+3)*NBUCK+t];
  for(; b<HB; ++b) v += bcnt2d[b*NBUCK+t];
  s[t]=v;
  __syncthreads();
  for(int off=1; off<NBUCK; off<<=1){
    int a=(t>=off)? s[t-off]:0;
    __syncthreads();
    s[t]+=a;
    __syncthreads();
  }
  int excl = s[t]-v;
  gcur[t]=excl;
  gbase[t]=excl;
  if(t==NBUCK-1) gbase[NBUCK]=s[t];
}

// packed pair: src (17b) | dstlocal<<17 (10b)
__global__ __launch_bounds__(512) void k_reorder(
    const int* __restrict__ src, const int* __restrict__ dst,
    int* __restrict__ gcur, int* __restrict__ pairs, int n){
  __shared__ int lh[NBUCK];
  __shared__ int lbase[NBUCK];
  int t=threadIdx.x;
  if(t<NBUCK) lh[t]=0;
  __syncthreads();
  int base = blockIdx.x*EPB;
  int bb[8], rr[8], pv[8];
  #pragma unroll
  for(int j=0;j<8;j++){
    int e = base + t + j*512;
    if(e<n){
      int d=dst[e];
      int b=d>>10;
      rr[j]=atomicAdd(&lh[b],1);
      bb[j]=b;
      pv[j]=src[e] | ((d & 1023)<<17);
    } else bb[j]=-1;
  }
  __syncthreads();
  if(t<NBUCK && lh[t]) lbase[t]=atomicAdd(&gcur[t], lh[t]);
  __syncthreads();
  #pragma unroll
  for(int j=0;j<8;j++){
    if(bb[j]>=0){
      int pos = lbase[bb[j]] + rr[j];
      pairs[pos] = pv[j];
    }
  }
}

// One block per bucket: LDS hist over 1024 local nodes -> scan -> rowptr/invdeg
// -> LDS-cursor scatter into the bucket's private csr window (one XCD's L2).
__global__ __launch_bounds__(512) void k_bucket_csr(
    const int* __restrict__ pairs, const int* __restrict__ gbase,
    int* __restrict__ rowptr, float* __restrict__ invdeg,
    int* __restrict__ csr, int nnodes, int nedges){
  __shared__ int cnt[BNODES];
  __shared__ int part[512];
  int t=threadIdx.x, b=blockIdx.x;
  int nb0 = b*BNODES;
  int e0 = gbase[b], e1 = gbase[b+1];
  cnt[t]=0; cnt[t+512]=0;
  __syncthreads();
  for(int e=e0+t; e<e1; e+=512) atomicAdd(&cnt[pairs[e]>>17], 1);
  __syncthreads();
  int c0 = cnt[2*t], c1 = cnt[2*t+1];
  part[t] = c0+c1;
  __syncthreads();
  for(int off=1; off<512; off<<=1){
    int a=(t>=off)? part[t-off]:0;
    __syncthreads();
    part[t]+=a;
    __syncthreads();
  }
  int base = part[t]-(c0+c1);
  int ex0 = base, ex1 = base+c0;
  int n_0 = nb0+2*t, n_1 = nb0+2*t+1;
  if(n_0<nnodes){ rowptr[n_0]=e0+ex0; invdeg[n_0]=1.0f/fmaxf((float)c0,1.0f); }
  if(n_1<nnodes){ rowptr[n_1]=e0+ex1; invdeg[n_1]=1.0f/fmaxf((float)c1,1.0f); }
  if(b==0 && t==0) rowptr[nnodes]=nedges;
  cnt[2*t]=ex0; cnt[2*t+1]=ex1;      // become cursors
  __syncthreads();
  for(int e=e0+t; e<e1; e+=512){
    int p = pairs[e];
    int pos = atomicAdd(&cnt[p>>17], 1);
    csr[e0+pos] = p & 0x1FFFF;
  }
}

// fp8 gather: TWO nodes per wave, 8B/lane (r16-proven) + JAMMED tails:
// A and B tail batches advance together so two independent miss chains
// stay in flight. agg[node] = mean of neighbor rows -> bf16.
__global__ __launch_bounds__(512) void k_gather(
    const uchar_t* __restrict__ hin8, ushort_t* __restrict__ agg,
    const int* __restrict__ rowptr, const int* __restrict__ csr,
    const float* __restrict__ invdeg, int nnodes)
{
  int t=threadIdx.x;
  int lane=t&63, wid=t>>6;
  int nA=(blockIdx.x*8+wid)*2;
  if(nA>=nnodes) return;
  int nB=nA+1;
  bool hasB = (nB<nnodes);
  int slot=lane>>3, c=lane&7;
  int rA0=rowptr[nA], rA1=rowptr[nA+1];
  int rB0=rA1, rB1=hasB? rowptr[nB+1] : rA1;
  float idgA=invdeg[nA];
  float idgB=hasB? invdeg[nB] : 0.f;
  float aA[8]={0,0,0,0,0,0,0,0}, aB[8]={0,0,0,0,0,0,0,0};
  int ca=(rA1>rA0)? rA1-1 : 0;
  int cb=(rB1>rB0)? rB1-1 : 0;

  {  // prologue: batch0 of A and B in flight together (4 gather VMEMs)
    int i1=rA0+slot, i2=rA0+8+slot;
    int j1=rB0+slot, j2=rB0+8+slot;
    int sA1=csr[min(i1,ca)], sA2=csr[min(i2,ca)];
    int sB1=csr[min(j1,cb)], sB2=csr[min(j2,cb)];
    uint2 uA1=*(const uint2*)&hin8[(size_t)sA1*HD + c*8];
    uint2 uA2=*(const uint2*)&hin8[(size_t)sA2*HD + c*8];
    uint2 uB1=*(const uint2*)&hin8[(size_t)sB1*HD + c*8];
    uint2 uB2=*(const uint2*)&hin8[(size_t)sB2*HD + c*8];
    acc8(aA,uA1.x,uA1.y,(i1<rA1)?1.f:0.f);
    acc8(aA,uA2.x,uA2.y,(i2<rA1)?1.f:0.f);
    acc8(aB,uB1.x,uB1.y,(j1<rB1)?1.f:0.f);
    acc8(aB,uB2.x,uB2.y,(j2<rB1)?1.f:0.f);
  }
  int eA=rA0+16, eB=rB0+16;
  for(; eA<rA1 && eB<rB1; eA+=16, eB+=16){   // jammed: 2 chains in flight
    int i1=eA+slot, i2=eA+8+slot;
    int j1=eB+slot, j2=eB+8+slot;
    int sA1=csr[min(i1,ca)], sA2=csr[min(i2,ca)];
    int sB1=csr[min(j1,cb)], sB2=csr[min(j2,cb)];
    uint2 uA1=*(const uint2*)&hin8[(size_t)sA1*HD + c*8];
    uint2 uA2=*(const uint2*)&hin8[(size_t)sA2*HD + c*8];
    uint2 uB1=*(const uint2*)&hin8[(size_t)sB1*HD + c*8];
    uint2 uB2=*(const uint2*)&hin8[(size_t)sB2*HD + c*8];
    acc8(aA,uA1.x,uA1.y,(i1<rA1)?1.f:0.f);
    acc8(aA,uA2.x,uA2.y,(i2<rA1)?1.f:0.f);
    acc8(aB,uB1.x,uB1.y,(j1<rB1)?1.f:0.f);
    acc8(aB,uB2.x,uB2.y,(j2<rB1)?1.f:0.f);
  }
  for(; eA<rA1; eA+=16){
    int i1=eA+slot, i2=eA+8+slot;
    int s1=csr[min(i1,ca)], s2=csr[min(i2,ca)];
    uint2 u1=*(const uint2*)&hin8[(size_t)s1*HD + c*8];
    uint2 u2=*(const uint2*)&hin8[(size_t)s2*HD + c*8];
    acc8(aA,u1.x,u1.y,(i1<rA1)?1.f:0.f);
    acc8(aA,u2.x,u2.y,(i2<rA1)?1.f:0.f);
  }
  for(; eB<rB1; eB+=16){
    int i1=eB+slot, i2=eB+8+slot;
    int s1=csr[min(i1,cb)], s2=csr[min(i2,cb)];
    uint2 u1=*(const uint2*)&hin8[(size_t)s1*HD + c*8];
    uint2 u2=*(const uint2*)&hin8[(size_t)s2*HD + c*8];
    acc8(aB,u1.x,u1.y,(i1<rB1)?1.f:0.f);
    acc8(aB,u2.x,u2.y,(i2<rB1)?1.f:0.f);
  }
  #pragma unroll
  for(int off=8; off<64; off<<=1){
    #pragma unroll
    for(int j=0;j<8;j++){
      aA[j] += __shfl_xor(aA[j], off, 64);
      aB[j] += __shfl_xor(aB[j], off, 64);
    }
  }
  if(slot==0){
    ushort8_t o;
    #pragma unroll
    for(int j=0;j<8;j++) o[j] = f2bf(aA[j]*idgA);
    *(ushort8_t*)&agg[(size_t)nA*HD + c*8] = o;
    if(hasB){
      #pragma unroll
      for(int j=0;j<8;j++) o[j] = f2bf(aB[j]*idgB);
      *(ushort8_t*)&agg[(size_t)nB*HD + c*8] = o;
    }
  }
}

// MFMA dense: C[N,64] = relu([agg|h] @ [Wl;Wr] + b), fused JK dot (+sigmoid).
// Epilogue also emits the fp8 copy of h for the next layer's gather.
__global__ __launch_bounds__(256) void k_dense(
    const ushort_t* __restrict__ hin, const ushort_t* __restrict__ agg,
    ushort_t* __restrict__ hout, uchar_t* __restrict__ h8out,
    const float* __restrict__ Wl, const float* __restrict__ bvec, const float* __restrict__ Wr,
    const float* __restrict__ wseg, const float* __restrict__ blin,
    float* __restrict__ partial, float* __restrict__ finout,
    int first, int nnodes)
{
  __shared__ ushort_t sWt[64][136];   // W^T bf16: [col][k]; 272B stride -> 2-way (free)
  __shared__ ushort_t sOut[TILE][72]; // relu'd outputs bf16
  __shared__ float sB[64], sS[64];
  int t = threadIdx.x;
  int n0 = blockIdx.x*TILE;

  {
    int col = t & 63;
    int k0  = (t >> 6) * 32;
    #pragma unroll
    for (int j = 0; j < 32; ++j) {
      int k = k0 + j;
      float wv = (k < 64) ? Wl[k*64 + col] : Wr[(k-64)*64 + col];
      sWt[col][k] = f2bf(wv);
    }
  }
  if(t<64){ sB[t]=bvec[t]; sS[t]=wseg[t]; }
  __syncthreads();

  int lane = t & 63, wv_ = t >> 6;
  int r16 = lane & 15, g4 = lane >> 4;
  int nbase = n0 + wv_*32;

  float4_t acc[2][4];
  #pragma unroll
  for(int mt=0;mt<2;mt++)
    #pragma unroll
    for(int ct=0;ct<4;ct++)
      #pragma unroll
      for(int r=0;r<4;r++) acc[mt][ct][r]=0.f;

  #pragma unroll
  for (int ks = 0; ks < 4; ++ks) {
    const ushort_t* abuf = (ks < 2) ? agg : hin;   // k<64: agg, k>=64: h
    int koff = (ks & 1)*32 + g4*8;
    short8_t aF[2];
    #pragma unroll
    for (int mt = 0; mt < 2; ++mt) {
      int node = nbase + mt*16 + r16;
      if (node >= nnodes) node = nnodes-1;         // clamp; stores guarded
      aF[mt] = *(const short8_t*)&abuf[(size_t)node*HD + koff];
    }
    #pragma unroll
    for (int ct = 0; ct < 4; ++ct) {
      short8_t bF = *(const short8_t*)&sWt[ct*16 + r16][ks*32 + g4*8];
      acc[0][ct] = __builtin_amdgcn_mfma_f32_16x16x32_bf16(aF[0], bF, acc[0][ct], 0,0,0);
      acc[1][ct] = __builtin_amdgcn_mfma_f32_16x16x32_bf16(aF[1], bF, acc[1][ct], 0,0,0);
    }
  }

  #pragma unroll
  for (int mt = 0; mt < 2; ++mt)
    #pragma unroll
    for (int ct = 0; ct < 4; ++ct) {
      int col = ct*16 + r16;
      #pragma unroll
      for (int r = 0; r < 4; ++r) {
        int row = g4*4 + r;
        float v = fmaxf(acc[mt][ct][r] + sB[col], 0.f);
        sOut[wv_*32 + mt*16 + row][col] = f2bf(v);
      }
    }
  __syncthreads();

  // pass 2: vectorized stores (bf16 + fp8) + JK dot + partial/sigmoid
  {
    int nl = t >> 1, half = t & 1;
    int node = n0 + nl;
    float p = 0.f;
    #pragma unroll
    for (int i = 0; i < 4; ++i) {
      int c0 = half*32 + i*8;
      ushort8_t v = *(const ushort8_t*)&sOut[nl][c0];
      float fv[8];
      #pragma unroll
      for (int j = 0; j < 8; ++j){ fv[j]=bf2f(v[j]); p = fmaf(fv[j], sS[c0+j], p); }
      if (!finout && node < nnodes){
        *(ushort8_t*)&hout[(size_t)node*HD + c0] = v;
        int q0 = __builtin_amdgcn_cvt_pk_fp8_f32(fv[0], fv[1], 0, false);
        q0     = __builtin_amdgcn_cvt_pk_fp8_f32(fv[2], fv[3], q0, true);
        int q1 = __builtin_amdgcn_cvt_pk_fp8_f32(fv[4], fv[5], 0, false);
        q1     = __builtin_amdgcn_cvt_pk_fp8_f32(fv[6], fv[7], q1, true);
        uint2 st; st.x=(unsigned)q0; st.y=(unsigned)q1;
        *(uint2*)&h8out[(size_t)node*HD + c0] = st;
      }
    }
    p += __shfl_xor(p, 1, 64);
    if (half == 0 && node < nnodes) {
      float q = first ? (blin[0] + p) : (partial[node] + p);
      if (finout) finout[node] = 1.0f/(1.0f+expf(-q));
      else partial[node] = q;
    }
  }
}

extern "C" void kernel_launch(void* const* d_in, const int* in_sizes, int n_in,
                              void* d_out, int out_size, void* d_ws, size_t ws_size,
                              hipStream_t stream){
  const float* x    =(const float*)d_in[0];
  const int*   ei   =(const int*)  d_in[1];
  const float* W1l  =(const float*)d_in[2];
  const float* b1   =(const float*)d_in[3];
  const float* W1r  =(const float*)d_in[4];
  const float* W2l  =(const float*)d_in[5];
  const float* b2   =(const float*)d_in[6];
  const float* W2r  =(const float*)d_in[7];
  const float* W3l  =(const float*)d_in[8];
  const float* b3   =(const float*)d_in[9];
  const float* W3r  =(const float*)d_in[10];
  const float* Wlin =(const float*)d_in[11];
  const float* blin =(const float*)d_in[12];
  float* out=(float*)d_out;

  const int N=N_NODES, E=N_EDGES;
  char* ws=(char*)d_ws;
  size_t off=0;
  auto take=[&](size_t bytes)->char*{ char* p=ws+off; off=(off+bytes+255)&~(size_t)255; return p; };
  int*      bcnt2d   =(int*)     take((size_t)HB*NBUCK*4);
  int*      gcur     =(int*)     take((size_t)NBUCK*4);
  int*      gbase    =(int*)     take((size_t)(NBUCK+1)*4);
  int*      rowptr   =(int*)     take((size_t)(N+1)*4);
  int*      csr      =(int*)     take((size_t)E*4);
  int*      pairs    =(int*)     take((size_t)E*4);
  float*    invdeg   =(float*)   take((size_t)N*4);
  ushort_t* xbf      =(ushort_t*)take((size_t)N*HD*2);
  ushort_t* hbfA     =(ushort_t*)take((size_t)N*HD*2);
  ushort_t* hbfB     =(ushort_t*)take((size_t)N*HD*2);
  ushort_t* aggbf    =(ushort_t*)take((size_t)N*HD*2);
  uchar_t*  x8       =(uchar_t*) take((size_t)N*HD);
  uchar_t*  h8A      =(uchar_t*) take((size_t)N*HD);
  uchar_t*  h8B      =(uchar_t*) take((size_t)N*HD);
  float*    pacc     =(float*)   take((size_t)N*4);

  const int RB=(E+EPB-1)/EPB;           // 391 (reorder)
  const int CB=(N*HD/4+511)/512;        // 3125 fused convert+hist blocks
  const int BB=(N+BNODES-1)/BNODES;     // 98 buckets

  k_convert_hist<<<CB, 512, 0, stream>>>(x, xbf, x8, ei+E, bcnt2d, N*HD, E);
  k_scan128     <<<1, NBUCK, 0, stream>>>(bcnt2d, gcur, gbase);
  k_reorder     <<<RB, 512, 0, stream>>>(ei, ei+E, gcur, pairs, E);
  k_bucket_csr  <<<BB, 512, 0, stream>>>(pairs, gbase, rowptr, invdeg, csr, N, E);

  dim3 gg((N+15)/16);                   // 6250 blocks, 2 nodes/wave
  dim3 gd((N+TILE-1)/TILE);

  k_gather<<<gg, 512, 0, stream>>>(x8,  aggbf, rowptr, csr, invdeg, N);
  k_dense <<<gd, 256, 0, stream>>>(xbf,  aggbf, hbfA, h8A, W1l,b1,W1r, Wlin+0,   blin, pacc, (float*)nullptr, 1, N);
  k_gather<<<gg, 512, 0, stream>>>(h8A, aggbf, rowptr, csr, invdeg, N);
  k_dense <<<gd, 256, 0, stream>>>(hbfA, aggbf, hbfB, h8B, W2l,b2,W2r, Wlin+64,  blin, pacc, (float*)nullptr, 0, N);
  k_gather<<<gg, 512, 0, stream>>>(h8B, aggbf, rowptr, csr, invdeg, N);
  k_dense <<<gd, 256, 0, stream>>>(hbfB, aggbf, hbfA, h8A, W3l,b3,W3r, Wlin+128, blin, pacc, out, 0, N);
}